// Round 12
// baseline (358.407 us; speedup 1.0000x reference)
//
#include <hip/hip_runtime.h>

#define NPTS   16384
#define KCODES 8192
#define DDIM   256
#define HWSZ   1024
#define CHW    (DDIM * HWSZ)          // 262144
#define OUT_ELEMS 4194304
#define LOSS_OFF  OUT_ELEMS
#define IDX_OFF   (OUT_ELEMS + 1)

#define PTB    32                // points per block (1 pt-group); 512 blocks -> 2/CU
#define NTILE  64                // code tiles of 128
#define IMG_US 16384             // ushorts per image: hi[128][64] + lo[128][64]
#define IMG_B  32768
#define SE_OFF_B (256 * IMG_B)   // 8 MB of images, then se[8192] f32

typedef _Float16 half_t;
typedef __attribute__((ext_vector_type(8)))  _Float16 half8;
typedef __attribute__((ext_vector_type(16))) float    v16f;

union HU { _Float16 h; unsigned short u; };

#define GLD16(gp, lp) __builtin_amdgcn_global_load_lds( \
    (const __attribute__((address_space(1))) unsigned int*)(gp), \
    (__attribute__((address_space(3))) unsigned int*)(lp), 16, 0, 0)

// ws images: img = (c>>7)*4 + (k>>6). Row r=c&127 holds its 64 k f16 with
// 16B-block swizzle blk^(r&7). Split formulas BIT-IDENTICAL to R7-R11.
__global__ void prep_kernel(const float* __restrict__ emb,
                            unsigned short* __restrict__ eimg,
                            float* __restrict__ se)
{
    const int gw   = (blockIdx.x * 256 + threadIdx.x) >> 6;   // 0..1023
    const int lane = threadIdx.x & 63;
    for (int i = 0; i < 8; ++i) {
        const int c = gw * 8 + i;                             // code 0..8191
        const float4 v = *(const float4*)(emb + (size_t)c * DDIM + lane * 4);
        float ps = v.x * v.x;
        ps = fmaf(v.y, v.y, ps); ps = fmaf(v.z, v.z, ps); ps = fmaf(v.w, v.w, ps);
        float tot = ps;
        #pragma unroll
        for (int off = 1; off < 64; off <<= 1) tot += __shfl_xor(tot, off);
        if (lane == 0) se[c] = tot;
        const float E0 = v.x * 64.f, E1 = v.y * 64.f, E2 = v.z * 64.f, E3 = v.w * 64.f;
        const half_t h0 = (half_t)E0, h1 = (half_t)E1, h2 = (half_t)E2, h3 = (half_t)E3;
        const half_t l0 = (half_t)((E0 - (float)h0) * 2048.f);
        const half_t l1 = (half_t)((E1 - (float)h1) * 2048.f);
        const half_t l2 = (half_t)((E2 - (float)h2) * 2048.f);
        const half_t l3 = (half_t)((E3 - (float)h3) * 2048.f);
        HU uha, uhb, uhc, uhd, ula, ulb, ulc, uld;
        uha.h = h0; uhb.h = h1; uhc.h = h2; uhd.h = h3;
        ula.h = l0; ulb.h = l1; ulc.h = l2; uld.h = l3;
        const unsigned int wh0 = (unsigned)uha.u | ((unsigned)uhb.u << 16);
        const unsigned int wh1 = (unsigned)uhc.u | ((unsigned)uhd.u << 16);
        const unsigned int wl0 = (unsigned)ula.u | ((unsigned)ulb.u << 16);
        const unsigned int wl1 = (unsigned)ulc.u | ((unsigned)uld.u << 16);
        const int kl  = lane * 4;                 // k 0..255
        const int img = (c >> 7) * 4 + (kl >> 6);
        const int k64 = kl & 63;
        const int r   = c & 127;
        const int blk = (k64 >> 3) ^ (r & 7);     // swizzled 16B block
        const size_t base = (size_t)img * IMG_US + r * 64 + blk * 8 + (k64 & 7);
        *(unsigned int*)&eimg[base]            = wh0;
        *(unsigned int*)&eimg[base + 2]        = wh1;
        *(unsigned int*)&eimg[base + 8192]     = wl0;
        *(unsigned int*)&eimg[base + 8192 + 2] = wl1;
    }
}

// m = xh.eh + (xh.el + xl.eh)*2^-11 via 32x32x16 f16 MFMA; A in registers.
// dist = fl(fl(s+se) - 2m) fp32; GLOBAL lowest-index tie-break (within-lane
// update is tie-aware because tile visit order is rotated per block).
// NOTE: never pass a second __launch_bounds__ arg on this toolchain (R4).
__launch_bounds__(256)
__global__ void vq_kernel(const float* __restrict__ x,
                          const unsigned short* __restrict__ eimg,
                          const float* __restrict__ wse,
                          const float* __restrict__ emb,
                          float* __restrict__ out)
{
    __shared__ __align__(16) unsigned short ldsE[2][IMG_US];  // 65536 B dbuf
    __shared__ float  ldsS[PTB];
    __shared__ float  ldsFD[4][32];
    __shared__ int    ldsFI[4][32];
    __shared__ int    ldsI[PTB];
    __shared__ double ldsL[4];

    const int t    = threadIdx.x;
    const int lane = t & 63;
    const int w    = t >> 6;          // 0..3
    const int cg   = w;               // code-group (0..3)
    const int n0   = blockIdx.x * PTB;
    const int b    = n0 / HWSZ;
    const int hw0  = n0 % HWSZ;
    const int tstart = blockIdx.x & 63;            // tile rotation (L2 decongestion)
    const float* xs = x + (size_t)b * CHW + hw0;   // xs[c*HWSZ + p]

    // ---- DMA staging: 32KB image; wave w covers bytes [w*8192, +8192) ----
    #define STAGE(img, buf) do { \
        const char* _g = (const char*)eimg + (size_t)(img) * IMG_B + w * 8192 + lane * 16; \
        char* _l = (char*)ldsE[buf] + w * 8192; \
        GLD16(_g,        _l); \
        GLD16(_g + 1024, _l + 1024); \
        GLD16(_g + 2048, _l + 2048); \
        GLD16(_g + 3072, _l + 3072); \
        GLD16(_g + 4096, _l + 4096); \
        GLD16(_g + 5120, _l + 5120); \
        GLD16(_g + 6144, _l + 6144); \
        GLD16(_g + 7168, _l + 7168); \
    } while (0)

    STAGE(tstart * 4, 0);   // bootstrap seq 0 (drained by prologue barrier)

    // ---- prologue: x -> registers (A-frag: row=lane&31, k=(lane>>5)*8+j) ----
    const int prow  = lane & 31;
    const int khalf = (lane >> 5) * 8;
    const float* xp = xs + prow;
    half8 xh[16], xl[16];
    float sq = 0.f;
    #pragma unroll
    for (int xc = 0; xc < 16; ++xc) {
        #pragma unroll
        for (int j = 0; j < 8; ++j) {
            const int c = xc * 16 + khalf + j;
            const float v = xp[(size_t)c * HWSZ];
            const half_t hh = (half_t)v;
            const half_t hl = (half_t)((v - (float)hh) * 2048.0f);
            xh[xc][j] = hh;
            xl[xc][j] = hl;
            sq = fmaf(v, v, sq);
        }
    }
    const float s_p = sq + __shfl_xor(sq, 32);     // ||x_p||^2 (order-invariant for argmin)
    if (w == 0 && lane < 32) ldsS[lane] = s_p;
    __syncthreads();                               // ldsS visible; bootstrap image drained

    float s_frag[16];
    #pragma unroll
    for (int q = 0; q < 16; ++q) {
        const int rl = (q & 3) + 8 * (q >> 2) + 4 * (lane >> 5);
        s_frag[q] = ldsS[rl];
    }

    float best_d[16]; int best_i[16];
    #pragma unroll
    for (int q = 0; q < 16; ++q) { best_d[q] = 3.4e38f; best_i[q] = 0x7fffffff; }

    const int rr  = cg * 32 + (lane & 31);         // B row within 128-code tile
    const int rb7 = rr & 7;
    float se_reg = 0.f;
    v16f acc_hh, acc_hl;

    for (int tt = 0; tt < NTILE; ++tt) {
        const int ta = (tt + tstart) & 63;         // actual tile (rotated)
        #pragma unroll
        for (int q = 0; q < 16; ++q) { acc_hh[q] = 0.f; acc_hl[q] = 0.f; }
        #pragma unroll
        for (int kc = 0; kc < 4; ++kc) {
            const int seq = tt * 4 + kc;
            const int buf = seq & 1;
            __syncthreads();                       // drain DMA for buf; readers of other buf done
            {
                int ns = seq + 1;
                if (ns == 256) ns = 0;             // harmless dummy
                const int nta = (((ns >> 2)) + tstart) & 63;
                STAGE(nta * 4 + (ns & 3), ns & 1); // async under compute
            }
            if (kc == 2) se_reg = wse[ta * 128 + rr];
            #pragma unroll
            for (int s = 0; s < 4; ++s) {
                const int bblk = (s * 2 + (lane >> 5)) ^ rb7;
                const unsigned short* bp = &ldsE[buf][rr * 64 + bblk * 8];
                const half8 bh = *(const half8*)bp;
                const half8 bl = *(const half8*)(bp + 8192);
                const int xc = kc * 4 + s;         // compile-time (both loops unrolled)
                acc_hh = __builtin_amdgcn_mfma_f32_32x32x16_f16(xh[xc], bh, acc_hh, 0, 0, 0);
                acc_hl = __builtin_amdgcn_mfma_f32_32x32x16_f16(xh[xc], bl, acc_hl, 0, 0, 0);
                acc_hl = __builtin_amdgcn_mfma_f32_32x32x16_f16(xl[xc], bh, acc_hl, 0, 0, 0);
            }
        }
        // ---- tile finalize: dist = fl(fl(s+se) - 2m); tie-aware (rotation) ----
        const int code = ta * 128 + rr;
        #pragma unroll
        for (int q = 0; q < 16; ++q) {
            const float m = fmaf(acc_hl[q], 4.8828125e-4f, acc_hh[q]) * 0.015625f;
            const float T = s_frag[q] + se_reg;
            const float d = fmaf(-2.0f, m, T);
            if (d < best_d[q] || (d == best_d[q] && code < best_i[q])) {
                best_d[q] = d; best_i[q] = code;
            }
        }
    }

    // ---- argmin: butterfly over 32 cols (lexicographic), per 32-lane half ----
    #pragma unroll
    for (int off = 1; off < 32; off <<= 1) {
        #pragma unroll
        for (int q = 0; q < 16; ++q) {
            const float d2 = __shfl_xor(best_d[q], off);
            const int   i2 = __shfl_xor(best_i[q], off);
            if (d2 < best_d[q] || (d2 == best_d[q] && i2 < best_i[q])) {
                best_d[q] = d2; best_i[q] = i2;
            }
        }
    }
    if ((lane & 31) == 0) {
        #pragma unroll
        for (int q = 0; q < 16; ++q) {
            const int rl = (q & 3) + 8 * (q >> 2) + 4 * (lane >> 5);
            ldsFD[w][rl] = best_d[q];
            ldsFI[w][rl] = best_i[q];
        }
    }
    __syncthreads();
    if (t < PTB) {
        float bd = ldsFD[0][t];
        int   bi = ldsFI[0][t];
        #pragma unroll
        for (int c2 = 1; c2 < 4; ++c2) {
            const float d2 = ldsFD[c2][t];
            const int   i2 = ldsFI[c2][t];
            if (d2 < bd || (d2 == bd && i2 < bi)) { bd = d2; bi = i2; }
        }
        ldsI[t] = bi;
        out[(size_t)IDX_OFF + n0 + t] = (float)bi;
    }
    __syncthreads();

    // ---- epilogue: gather e row, straight-through out, loss partial ----
    double lsum = 0.0;
    {
        const int p   = t & 31;
        const int cgp = t >> 5;                    // 0..7
        const int row = ldsI[p];
        const float* erow = emb + (size_t)row * DDIM;
        float* ob = out + (size_t)b * CHW + hw0 + p;
        for (int q = 0; q < 32; ++q) {
            const int c = cgp * 32 + q;
            const float e  = erow[c];
            const float xx = xs[(size_t)c * HWSZ + p];
            const float diff = e - xx;             // fl(x_q - xt)
            ob[(size_t)c * HWSZ] = xx + diff;      // straight-through rounding
            lsum += (double)diff * (double)diff;
        }
    }
    #pragma unroll
    for (int off = 32; off > 0; off >>= 1)
        lsum += __shfl_xor(lsum, off);
    if ((t & 63) == 0) ldsL[t >> 6] = lsum;
    __syncthreads();
    if (t == 0) {
        double tot = 0.0;
        #pragma unroll
        for (int wv = 0; wv < 4; ++wv) tot += ldsL[wv];
        atomicAdd(&out[LOSS_OFF], (float)(tot * (1.25 / 4194304.0)));
    }
}

extern "C" void kernel_launch(void* const* d_in, const int* in_sizes, int n_in,
                              void* d_out, int out_size, void* d_ws, size_t ws_size,
                              hipStream_t stream) {
    (void)in_sizes; (void)n_in; (void)out_size; (void)ws_size;
    const float* x   = (const float*)d_in[0];
    const float* emb = (const float*)d_in[1];
    float* out = (float*)d_out;
    unsigned short* eimg = (unsigned short*)d_ws;
    float*          wse  = (float*)((char*)d_ws + SE_OFF_B);
    (void)hipMemsetAsync((char*)d_out + (size_t)LOSS_OFF * sizeof(float), 0, sizeof(float), stream);
    prep_kernel<<<256, 256, 0, stream>>>(emb, eimg, wse);
    vq_kernel<<<NPTS / PTB, 256, 0, stream>>>(x, eimg, wse, emb, out);
}

// Round 13
// 350.783 us; speedup vs baseline: 1.0217x; 1.0217x over previous
//
#include <hip/hip_runtime.h>

#define NPTS   16384
#define KCODES 8192
#define DDIM   256
#define HWSZ   1024
#define CHW    (DDIM * HWSZ)          // 262144
#define OUT_ELEMS 4194304
#define LOSS_OFF  OUT_ELEMS
#define IDX_OFF   (OUT_ELEMS + 1)

#define PTB    64                // points per block; 256 blocks = 1/CU
#define NTILE  64                // code tiles of 128
#define SE_OFF_B (8 * 1024 * 1024)   // 8 MB fragment images, then se[8192] f32

typedef _Float16 half_t;
typedef __attribute__((ext_vector_type(8)))  _Float16 half8;
typedef __attribute__((ext_vector_type(16))) float    v16f;

union HU { _Float16 h; unsigned short u; };

// ef layout (fragment-linear): seg = (tile*4+kc)*4+cg -> 8 KB block.
// Within: half8 index = s*128 + h*64 + lane  (s=0..3 K32-step, h=hi/lo,
// lane = hsel*32+col). The main loop's B loads are perfectly coalesced
// 1KB global_load_dwordx4 bursts straight into VGPRs — no LDS, no barriers.
// Split formulas BIT-IDENTICAL to R7-R12 (proven absmax 0).
__global__ void prep_frag(const float* __restrict__ emb,
                          unsigned short* __restrict__ ef)
{
    const int tid = blockIdx.x * 256 + threadIdx.x;   // 0..262143
    const int c   = tid >> 5;                         // code
    const int k8  = tid & 31;                         // 8-k chunk
    const float4 va = *(const float4*)(emb + (size_t)c * DDIM + k8 * 8);
    const float4 vb = *(const float4*)(emb + (size_t)c * DDIM + k8 * 8 + 4);
    const float f[8] = {va.x, va.y, va.z, va.w, vb.x, vb.y, vb.z, vb.w};
    unsigned int hw[4], lw[4];
    #pragma unroll
    for (int j = 0; j < 4; ++j) {
        HU ha, hb, la, lb;
        const float E0 = f[2*j] * 64.f, E1 = f[2*j+1] * 64.f;
        const half_t h0 = (half_t)E0, h1 = (half_t)E1;
        ha.h = h0; hb.h = h1;
        la.h = (half_t)((E0 - (float)h0) * 2048.f);
        lb.h = (half_t)((E1 - (float)h1) * 2048.f);
        hw[j] = (unsigned)ha.u | ((unsigned)hb.u << 16);
        lw[j] = (unsigned)la.u | ((unsigned)lb.u << 16);
    }
    const int tile = c >> 7, r = c & 127;
    const int cg = r >> 5, col = r & 31;
    const int kc = k8 >> 3, kk = k8 & 7;
    const int s = kk >> 1, hsel = kk & 1;
    const int lane = hsel * 32 + col;
    const size_t base = ((size_t)((tile * 4 + kc) * 4 + cg)) * 4096
                      + (size_t)(s * 2) * 512 + lane * 8;
    *(uint4*)&ef[base]       = make_uint4(hw[0], hw[1], hw[2], hw[3]);
    *(uint4*)&ef[base + 512] = make_uint4(lw[0], lw[1], lw[2], lw[3]);
}

// se[k] = ||e_k||^2 — same reduction tree as R11's prep (bit-identical).
__global__ void prep_se(const float* __restrict__ emb, float* __restrict__ se)
{
    const int gw   = (blockIdx.x * 256 + threadIdx.x) >> 6;  // 0..255
    const int lane = threadIdx.x & 63;
    for (int i = 0; i < 32; ++i) {
        const int c = gw * 32 + i;
        const float4 v = *(const float4*)(emb + (size_t)c * DDIM + lane * 4);
        float ps = v.x * v.x;
        ps = fmaf(v.y, v.y, ps); ps = fmaf(v.z, v.z, ps); ps = fmaf(v.w, v.w, ps);
        float tot = ps;
        #pragma unroll
        for (int off = 1; off < 64; off <<= 1) tot += __shfl_xor(tot, off);
        if (lane == 0) se[c] = tot;
    }
}

// m = xh.eh + (xh.el + xl.eh)*2^-11 via 32x32x16 f16 MFMA. B streams from
// global into register double-buffers (no LDS staging, NO barriers in the
// K-loop); x hi/lo in swizzled LDS (2-way b128 reads = free).
// dist = fl(fl(s+se) - 2m) fp32; ascending-code strict < (proven R1-R12).
// NOTE: never pass a second __launch_bounds__ arg on this toolchain (R4).
__launch_bounds__(512)
__global__ void vq_kernel(const float* __restrict__ x,
                          const unsigned short* __restrict__ ef,
                          const float* __restrict__ wse,
                          const float* __restrict__ emb,
                          float* __restrict__ out)
{
    __shared__ __align__(16) unsigned short ldsXH[PTB * 256];  // 32768 B
    __shared__ __align__(16) unsigned short ldsXL[PTB * 256];  // 32768 B
    __shared__ float  ldsS[PTB];
    __shared__ float  ldsFD[8][32];
    __shared__ int    ldsFI[8][32];
    __shared__ int    ldsI[PTB];
    __shared__ double ldsL[8];

    const int t    = threadIdx.x;
    const int lane = t & 63;
    const int w    = t >> 6;          // 0..7
    const int pg   = w >> 2;          // pt-group (0,1)
    const int cg   = w & 3;           // code-group (0..3)
    const int n0   = blockIdx.x * PTB;
    const int b    = n0 / HWSZ;
    const int hw0  = n0 % HWSZ;
    const float* xs = x + (size_t)b * CHW + hw0;   // xs[c*HWSZ + p]

    const int row  = pg * 32 + (lane & 31);        // point row (A / C-D col space)
    const int hsel = lane >> 5;
    const int rs7  = row & 7;

    // ---- prologue: waves 0,4 stage x hi/lo into swizzled LDS + s[p] ----
    if (cg == 0) {
        const float* xp = xs + row;
        float sq = 0.f;
        #pragma unroll
        for (int xc = 0; xc < 16; ++xc) {
            const int kb = xc * 2 + hsel;
            const int ao = row * 256 + ((kb ^ rs7) * 8);
            #pragma unroll
            for (int j = 0; j < 8; ++j) {
                const int c = xc * 16 + hsel * 8 + j;
                const float v = xp[(size_t)c * HWSZ];
                const half_t hh = (half_t)v;
                const half_t hl = (half_t)((v - (float)hh) * 2048.0f);
                HU u0; u0.h = hh; ldsXH[ao + j] = u0.u;
                HU u1; u1.h = hl; ldsXL[ao + j] = u1.u;
                sq = fmaf(v, v, sq);
            }
        }
        const float s_p = sq + __shfl_xor(sq, 32); // ||x_p||^2 (order = R11, bit-identical)
        if (lane < 32) ldsS[row] = s_p;
    }
    __syncthreads();

    float s_frag[16];
    #pragma unroll
    for (int q = 0; q < 16; ++q) {
        const int rl = (q & 3) + 8 * (q >> 2) + 4 * hsel;
        s_frag[q] = ldsS[pg * 32 + rl];
    }

    float best_d[16]; int best_i[16];
    #pragma unroll
    for (int q = 0; q < 16; ++q) { best_d[q] = 3.4e38f; best_i[q] = 0; }

    const int rr = cg * 32 + (lane & 31);          // code within 128-tile
    float se_reg = 0.f;
    v16f acc_hh, acc_hl;

    const half8* EB = (const half8*)ef;
    half8 BhA[4], BlA[4], BhB[4], BlB[4];

#define LOADB(seq, BH, BL) do { \
        const half8* _bp = EB + ((size_t)((((seq) & 255) * 4 + cg)) * 512) + lane; \
        BH[0] = _bp[0];   BL[0] = _bp[64]; \
        BH[1] = _bp[128]; BL[1] = _bp[192]; \
        BH[2] = _bp[256]; BL[2] = _bp[320]; \
        BH[3] = _bp[384]; BL[3] = _bp[448]; \
    } while (0)

#define MSTEP(kc, BH, BL) do { \
        _Pragma("unroll") \
        for (int s = 0; s < 4; ++s) { \
            const int kb = ((kc) * 4 + s) * 2 + hsel; \
            const int ao = row * 256 + ((kb ^ rs7) * 8); \
            const half8 ah = *(const half8*)&ldsXH[ao]; \
            const half8 al = *(const half8*)&ldsXL[ao]; \
            acc_hh = __builtin_amdgcn_mfma_f32_32x32x16_f16(ah, BH[s], acc_hh, 0, 0, 0); \
            acc_hl = __builtin_amdgcn_mfma_f32_32x32x16_f16(ah, BL[s], acc_hl, 0, 0, 0); \
            acc_hl = __builtin_amdgcn_mfma_f32_32x32x16_f16(al, BH[s], acc_hl, 0, 0, 0); \
        } \
    } while (0)

    LOADB(0, BhA, BlA);
    for (int tile = 0; tile < NTILE; ++tile) {
        #pragma unroll
        for (int q = 0; q < 16; ++q) { acc_hh[q] = 0.f; acc_hl[q] = 0.f; }
        const int s0 = tile * 4;
        LOADB(s0 + 1, BhB, BlB);
        MSTEP(0, BhA, BlA);
        LOADB(s0 + 2, BhA, BlA);
        MSTEP(1, BhB, BlB);
        se_reg = wse[tile * 128 + rr];             // L2-hot 32 KB table
        LOADB(s0 + 3, BhB, BlB);
        MSTEP(2, BhA, BlA);
        LOADB(s0 + 4, BhA, BlA);                   // wraps at end (harmless)
        MSTEP(3, BhB, BlB);
        // ---- tile finalize: dist = fl(fl(s+se) - 2m); ascending code order ----
        const int code = tile * 128 + rr;
        #pragma unroll
        for (int q = 0; q < 16; ++q) {
            const float m = fmaf(acc_hl[q], 4.8828125e-4f, acc_hh[q]) * 0.015625f;
            const float T = s_frag[q] + se_reg;
            const float d = fmaf(-2.0f, m, T);
            if (d < best_d[q]) { best_d[q] = d; best_i[q] = code; }
        }
    }
#undef LOADB
#undef MSTEP

    // ---- argmin: butterfly over 32 cols (lexicographic), per 32-lane half ----
    #pragma unroll
    for (int off = 1; off < 32; off <<= 1) {
        #pragma unroll
        for (int q = 0; q < 16; ++q) {
            const float d2 = __shfl_xor(best_d[q], off);
            const int   i2 = __shfl_xor(best_i[q], off);
            if (d2 < best_d[q] || (d2 == best_d[q] && i2 < best_i[q])) {
                best_d[q] = d2; best_i[q] = i2;
            }
        }
    }
    if ((lane & 31) == 0) {
        #pragma unroll
        for (int q = 0; q < 16; ++q) {
            const int rl = (q & 3) + 8 * (q >> 2) + 4 * hsel;
            ldsFD[w][rl] = best_d[q];
            ldsFI[w][rl] = best_i[q];
        }
    }
    __syncthreads();
    if (t < PTB) {
        const int pg2 = t >> 5, rl = t & 31;
        float bd = ldsFD[pg2 * 4][rl];
        int   bi = ldsFI[pg2 * 4][rl];
        #pragma unroll
        for (int c2 = 1; c2 < 4; ++c2) {
            const float d2 = ldsFD[pg2 * 4 + c2][rl];
            const int   i2 = ldsFI[pg2 * 4 + c2][rl];
            if (d2 < bd || (d2 == bd && i2 < bi)) { bd = d2; bi = i2; }
        }
        ldsI[t] = bi;
        out[(size_t)IDX_OFF + n0 + t] = (float)bi;
    }
    __syncthreads();

    // ---- epilogue: gather e row, straight-through out, loss partial ----
    double lsum = 0.0;
    {
        const int p   = t & 63;
        const int cgp = t >> 6;
        const int rowi = ldsI[p];
        const float* erow = emb + (size_t)rowi * DDIM;
        float* ob = out + (size_t)b * CHW + hw0 + p;
        for (int q = 0; q < 32; ++q) {
            const int c = cgp * 32 + q;
            const float e  = erow[c];
            const float xx = xs[(size_t)c * HWSZ + p];
            const float diff = e - xx;             // fl(x_q - xt)
            ob[(size_t)c * HWSZ] = xx + diff;      // straight-through rounding
            lsum += (double)diff * (double)diff;
        }
    }
    #pragma unroll
    for (int off = 32; off > 0; off >>= 1)
        lsum += __shfl_xor(lsum, off);
    if ((t & 63) == 0) ldsL[t >> 6] = lsum;
    __syncthreads();
    if (t == 0) {
        double tot = 0.0;
        #pragma unroll
        for (int wv = 0; wv < 8; ++wv) tot += ldsL[wv];
        atomicAdd(&out[LOSS_OFF], (float)(tot * (1.25 / 4194304.0)));
    }
}

extern "C" void kernel_launch(void* const* d_in, const int* in_sizes, int n_in,
                              void* d_out, int out_size, void* d_ws, size_t ws_size,
                              hipStream_t stream) {
    (void)in_sizes; (void)n_in; (void)out_size; (void)ws_size;
    const float* x   = (const float*)d_in[0];
    const float* emb = (const float*)d_in[1];
    float* out = (float*)d_out;
    unsigned short* ef  = (unsigned short*)d_ws;
    float*          wse = (float*)((char*)d_ws + SE_OFF_B);
    (void)hipMemsetAsync((char*)d_out + (size_t)LOSS_OFF * sizeof(float), 0, sizeof(float), stream);
    prep_frag<<<1024, 256, 0, stream>>>(emb, ef);
    prep_se<<<64, 256, 0, stream>>>(emb, wse);
    vq_kernel<<<NPTS / PTB, 512, 0, stream>>>(x, ef, wse, emb, out);
}